// Round 11
// baseline (79.963 us; speedup 1.0000x reference)
//
#include <hip/hip_runtime.h>
#include <hip/hip_bf16.h>

#define CCH 256      // channels
#define HH 128
#define WW 128
#define SS (HH*WW)   // 16384 pixels per batch
#define NB 8         // batch
#define NK 19        // keypoints
#define STILE 32     // pixels per block
#define NTIL (NB * (SS / STILE))   // 4096 tiles

typedef __attribute__((ext_vector_type(8))) short short8v;   // 8 bf16 = 4 VGPR (MFMA operand)
typedef __attribute__((ext_vector_type(4))) float f32x4;     // MFMA accum
typedef __attribute__((ext_vector_type(2))) float f32x2;     // native float2 (nt-store OK)

static __device__ __forceinline__ unsigned short f2bf(float x) {
    __hip_bfloat16 h = __float2bfloat16(x);
    return *reinterpret_cast<unsigned short*>(&h);
}
static __device__ __forceinline__ float bf2f(unsigned short u) {
    union { unsigned int i; float f; } z; z.i = ((unsigned int)u) << 16; return z.f;
}
static __device__ __forceinline__ float tanh_fast(float x) {
    // 1 - 2/(e^{2x}+1) with v_rcp (tolerance is generous; verified 0.0156)
    float e = __expf(2.f * x);
    return 1.f - 2.f * __builtin_amdgcn_rcpf(e + 1.f);
}
static __device__ __forceinline__ float sigmoid_fast(float z) {
    return __builtin_amdgcn_rcpf(1.f + __expf(-z));
}

// ---------------------------------------------------------------------------
// Kernel 1: precompute folded biases, delta weights, keypoint pixels, and
// img_fc_w rearranged to bf16 in MFMA A-fragment order:
//   Wfrag[((ks*16 + ot)*64 + lane)*8 + j] = bf16(W[ot*16 + (lane&15)][ks*32 + (lane>>4)*8 + j])
// ---------------------------------------------------------------------------
__global__ __launch_bounds__(256) void precompute_kernel(
    const float* __restrict__ kf,        // [B,K,3]
    const float* __restrict__ img_fc_w,  // [256,256]
    const float* __restrict__ img_fc_b,  // [256]
    const float* __restrict__ kp_proj_w, // [19,19]
    const float* __restrict__ kp_proj_b, // [19]
    const float* __restrict__ kp_fc_w,   // [256,19]
    const float* __restrict__ kp_fc_b,   // [256]
    float* __restrict__ cb,              // [256] combined bias
    float* __restrict__ delta,           // [256*19]
    int* __restrict__ pix,               // [B*K]
    unsigned short* __restrict__ Wfrag)  // [8*16*64*8]
{
    int t = threadIdx.x;
    {
        float acc = img_fc_b[t] + kp_fc_b[t];
        for (int k2 = 0; k2 < NK; ++k2) acc += kp_fc_w[t * NK + k2] * kp_proj_b[k2];
        cb[t] = acc;
        for (int k = 0; k < NK; ++k) {
            float d = 0.f;
            for (int k2 = 0; k2 < NK; ++k2) d += kp_fc_w[t * NK + k2] * kp_proj_w[k2 * NK + k];
            delta[t * NK + k] = d;
        }
    }
    if (t < NB * NK) {
        float kx = kf[t * 3 + 0], ky = kf[t * 3 + 1], vis = kf[t * 3 + 2];
        int p = -1;
        if (vis > 0.f) {
            int xi = (int)fminf(fmaxf(kx * (1.f / (float)WW), 0.f), (float)(WW - 1));
            int yi = (int)fminf(fmaxf(ky * (1.f / (float)HH), 0.f), (float)(HH - 1));
            p = yi * WW + xi;
        }
        pix[t] = p;
    }
    for (int g = t; g < 8 * 16 * 64; g += 256) {
        int lane = g & 63;
        int ot = (g >> 6) & 15;
        int ks = g >> 10;
        int o = ot * 16 + (lane & 15);
        int c0 = ks * 32 + (lane >> 4) * 8;
#pragma unroll
        for (int j = 0; j < 8; ++j)
            Wfrag[g * 8 + j] = f2bf(img_fc_w[o * CCH + c0 + j]);
    }
}

// ---------------------------------------------------------------------------
// Kernel 2: main fused GEMM + epilogue. 4096 blocks x 512 thr (8 waves).
// Tile: 256 o x 32 px. Wave w owns o in [w*32, w*32+32) (m=2), n=2 s-frags.
// Thread owns 8 channels (c0 = (t>>4)*8) x 2 pixels (pq = (t&15)*2).
// R11 changes vs R10: (1) keepalive asm forces all 8 staging loads in flight
// (R10's VGPR=28 proved the compiler serialized them); (2) K-loop software-
// pipelines A (L2) and B (LDS) fragment loads 2-deep with keepalives.
// Trades residency (2 blocks/CU) for per-wave ILP.
// ---------------------------------------------------------------------------
__global__ __launch_bounds__(512, 4) void main_kernel(
    const float* __restrict__ img,        // [B,256,16384]
    const unsigned short* __restrict__ Wfrag,
    const float* __restrict__ cb,         // [256]
    const float* __restrict__ aw,         // attn_fc_w [256]
    const float* __restrict__ attn_b,     // [1]
    float* __restrict__ out)              // [B,256,16384]
{
    __shared__ unsigned short Xl[STILE * 256];  // 16KB bf16 [s][c], 16B-block swizzled
    __shared__ float partial[8][STILE];
    __shared__ float cbl[256];
    __shared__ float awl[256];

    const int t = threadIdx.x;
    const int l = t & 63;        // lane
    const int w = t >> 6;        // wave 0..7

    // XCD-chunked bijective swizzle (4096 % 8 == 0).
    const int bid = blockIdx.x;
    const int swz = (bid & 7) * (NTIL / 8) + (bid >> 3);
    const int b = swz >> 9;                  // 512 tiles per batch
    const int sb = (swz & 511) * STILE;
    const float* imgb = img + (size_t)b * CCH * SS;

    if (t < 256) { cbl[t] = cb[t]; awl[t] = aw[t]; }

    const int pq = (t & 15) * 2;      // 2 pixels this thread owns
    const int cg = t >> 4;            // 0..31: channel octet (c0 = cg*8)
    const int c0 = cg * 8;

    // ---- phase 1: 8 float2 loads, ALL forced in flight, cvt, 2 ds_write ----
    {
        f32x2 xf2[8];
#pragma unroll
        for (int j = 0; j < 8; ++j)
            xf2[j] = *reinterpret_cast<const f32x2*>(imgb + (size_t)(c0 + j) * SS + sb + pq);
        // keepalive: all 8 values must be simultaneously live here -> the 8
        // global loads issue back-to-back before any conversion waits.
        asm volatile("" :: "v"(xf2[0]), "v"(xf2[1]), "v"(xf2[2]), "v"(xf2[3]),
                           "v"(xf2[4]), "v"(xf2[5]), "v"(xf2[6]), "v"(xf2[7]));
#pragma unroll
        for (int p = 0; p < 2; ++p) {
            int s = pq + p;
            short8v pk;
#pragma unroll
            for (int j = 0; j < 8; ++j)
                pk[j] = (short)f2bf(xf2[j][p]);
            int idx = s * 256 + ((cg ^ (s & 7)) << 3);
            *reinterpret_cast<short8v*>(&Xl[idx]) = pk;
        }
    }
    __syncthreads();

    // ---- phase 2: K loop, 2-deep pipelined A (L2) and B (LDS) fragments ----
    f32x4 acc[2][2];
#pragma unroll
    for (int m = 0; m < 2; ++m)
#pragma unroll
        for (int n = 0; n < 2; ++n)
            acc[m][n] = (f32x4){0.f, 0.f, 0.f, 0.f};

    const int s0 = (l & 15), s1 = 16 + (l & 15);

    short8v a0 = *reinterpret_cast<const short8v*>(
        &Wfrag[(((0 * 16 + (w * 2 + 0)) * 64) + l) * 8]);
    short8v a1 = *reinterpret_cast<const short8v*>(
        &Wfrag[(((0 * 16 + (w * 2 + 1)) * 64) + l) * 8]);
    short8v b0, b1;
    {
        const int cblk = 0 * 4 + (l >> 4);
        b0 = *reinterpret_cast<const short8v*>(&Xl[s0 * 256 + ((cblk ^ (s0 & 7)) << 3)]);
        b1 = *reinterpret_cast<const short8v*>(&Xl[s1 * 256 + ((cblk ^ (s1 & 7)) << 3)]);
    }

#pragma unroll
    for (int ks = 0; ks < 8; ++ks) {
        short8v an0, an1, bn0, bn1;
        if (ks < 7) {
            an0 = *reinterpret_cast<const short8v*>(
                &Wfrag[((((ks + 1) * 16 + (w * 2 + 0)) * 64) + l) * 8]);
            an1 = *reinterpret_cast<const short8v*>(
                &Wfrag[((((ks + 1) * 16 + (w * 2 + 1)) * 64) + l) * 8]);
            const int cblk = (ks + 1) * 4 + (l >> 4);
            bn0 = *reinterpret_cast<const short8v*>(
                &Xl[s0 * 256 + ((cblk ^ (s0 & 7)) << 3)]);
            bn1 = *reinterpret_cast<const short8v*>(
                &Xl[s1 * 256 + ((cblk ^ (s1 & 7)) << 3)]);
            // keepalive: next-step fragments are live before this step's MFMAs,
            // so their loads issue above the MFMA cluster.
            asm volatile("" :: "v"(an0), "v"(an1), "v"(bn0), "v"(bn1));
        }
        acc[0][0] = __builtin_amdgcn_mfma_f32_16x16x32_bf16(a0, b0, acc[0][0], 0, 0, 0);
        acc[1][0] = __builtin_amdgcn_mfma_f32_16x16x32_bf16(a1, b0, acc[1][0], 0, 0, 0);
        acc[0][1] = __builtin_amdgcn_mfma_f32_16x16x32_bf16(a0, b1, acc[0][1], 0, 0, 0);
        acc[1][1] = __builtin_amdgcn_mfma_f32_16x16x32_bf16(a1, b1, acc[1][1], 0, 0, 0);
        if (ks < 7) { a0 = an0; a1 = an1; b0 = bn0; b1 = bn1; }
    }

    // ---- phase 3: score[s] = sigmoid(attn_b + sum_o aw[o]*tanh(T[o,s]+cb[o]))
    // D layout: s = n*16 + (l&15), o = (w*2+m)*16 + (l>>4)*4 + r
    float p2[2];
#pragma unroll
    for (int n = 0; n < 2; ++n) {
        float accp = 0.f;
#pragma unroll
        for (int m = 0; m < 2; ++m)
#pragma unroll
            for (int r = 0; r < 4; ++r) {
                int o = (w * 2 + m) * 16 + ((l >> 4) << 2) + r;
                accp += awl[o] * tanh_fast(acc[m][n][r] + cbl[o]);
            }
        accp += __shfl_xor(accp, 16);
        accp += __shfl_xor(accp, 32);
        p2[n] = accp;
    }
    if (l < 16) {
        partial[w][l] = p2[0];
        partial[w][16 + l] = p2[1];
    }
    __syncthreads();

    // ---- phase 4: per-thread redundant final reduce + nt stores -----------
    {
        const float ab = attn_b[0];
        float z0 = ab, z1 = ab;
#pragma unroll
        for (int ww = 0; ww < 8; ++ww) {
            z0 += partial[ww][pq];
            z1 += partial[ww][pq + 1];
        }
        float s0v = sigmoid_fast(z0);
        float s1v = sigmoid_fast(z1);

        short8v v0, v1;
        {
            int i0 = pq * 256 + ((cg ^ (pq & 7)) << 3);
            int i1 = (pq + 1) * 256 + ((cg ^ ((pq + 1) & 7)) << 3);
            v0 = *reinterpret_cast<const short8v*>(&Xl[i0]);
            v1 = *reinterpret_cast<const short8v*>(&Xl[i1]);
        }
#pragma unroll
        for (int j = 0; j < 8; ++j) {
            f32x2 o2;
            o2[0] = bf2f((unsigned short)v0[j]) * s0v;
            o2[1] = bf2f((unsigned short)v1[j]) * s1v;
            __builtin_nontemporal_store(o2, reinterpret_cast<f32x2*>(
                out + (size_t)(b * CCH + c0 + j) * SS + sb + pq));
        }
    }
}

// ---------------------------------------------------------------------------
// Kernel 3: exact fp32 fixup for keypoint pixels (<=152). One block per (b,k).
// ---------------------------------------------------------------------------
__global__ __launch_bounds__(256) void fixup_kernel(
    const float* __restrict__ img,
    const float* __restrict__ img_fc_w,
    const float* __restrict__ aw,
    const float* __restrict__ attn_b,
    const float* __restrict__ cb,
    const float* __restrict__ delta,
    const int* __restrict__ pix,
    float* __restrict__ out)
{
    int bk = blockIdx.x;            // 0..151
    int b = bk / NK;
    int p = pix[bk];
    if (p < 0) return;              // uniform branch, before any barrier
    __shared__ float x[256];
    __shared__ float red[256];
    __shared__ float ssc;
    int t = threadIdx.x;
    const float* imgb = img + (size_t)b * CCH * SS;
    x[t] = imgb[(size_t)t * SS + p];
    __syncthreads();
    float dsum = 0.f;
    for (int k2 = 0; k2 < NK; ++k2)
        if (pix[b * NK + k2] == p) dsum += delta[t * NK + k2];
    float acc = cb[t] + dsum;
    for (int c = 0; c < CCH; ++c) acc += img_fc_w[t * CCH + c] * x[c];
    red[t] = aw[t] * tanh_fast(acc);
    __syncthreads();
    for (int off = 128; off > 0; off >>= 1) {
        if (t < off) red[t] += red[t + off];
        __syncthreads();
    }
    if (t == 0) ssc = sigmoid_fast(red[0] + attn_b[0]);
    __syncthreads();
    __builtin_nontemporal_store(x[t] * ssc, out + (size_t)(b * CCH + t) * SS + p);
}

// ---------------------------------------------------------------------------
extern "C" void kernel_launch(void* const* d_in, const int* in_sizes, int n_in,
                              void* d_out, int out_size, void* d_ws, size_t ws_size,
                              hipStream_t stream) {
    (void)in_sizes; (void)n_in; (void)out_size; (void)ws_size;
    const float* img       = (const float*)d_in[0];
    const float* kf        = (const float*)d_in[1];
    const float* img_fc_w  = (const float*)d_in[2];
    const float* img_fc_b  = (const float*)d_in[3];
    const float* kp_proj_w = (const float*)d_in[4];
    const float* kp_proj_b = (const float*)d_in[5];
    const float* kp_fc_w   = (const float*)d_in[6];
    const float* kp_fc_b   = (const float*)d_in[7];
    const float* attn_fc_w = (const float*)d_in[8];
    const float* attn_fc_b = (const float*)d_in[9];
    float* out = (float*)d_out;

    char* ws = (char*)d_ws;
    float* cb             = (float*)(ws);            // 256 f  ->   1024 B
    float* delta          = (float*)(ws + 1024);     // 4864 f -> 19456 B
    int*   pix            = (int*)  (ws + 20480);    // 152 i  ->   608 B
    unsigned short* Wfrag = (unsigned short*)(ws + 21504); // 131072 B

    precompute_kernel<<<1, 256, 0, stream>>>(kf, img_fc_w, img_fc_b, kp_proj_w,
                                             kp_proj_b, kp_fc_w, kp_fc_b,
                                             cb, delta, pix, Wfrag);
    main_kernel<<<NTIL, 512, 0, stream>>>(img, Wfrag, cb,
                                          attn_fc_w, attn_fc_b, out);
    fixup_kernel<<<NB * NK, 256, 0, stream>>>(img, img_fc_w, attn_fc_w, attn_fc_b,
                                              cb, delta, pix, out);
}